// Round 6
// baseline (255.882 us; speedup 1.0000x reference)
//
#include <hip/hip_runtime.h>
#include <cmath>

#define HH 256
#define WW 256
#define BB 64
#define OROWS 16
#define NSTRIP 16             // 256/16
#define TSTR 260              // tmp row stride (dwords): rows rotate 4 banks
#define NBLK (BB * NSTRIP)    // 1024 blocks; launch_bounds(256,4) => >=4 blocks/CU resident

static __device__ __forceinline__ float bin(float v) { return (v > 0.0f) ? 1.0f : 0.0f; }

// ---------------------------------------------------------------------------
// Kernel 0: reset the barrier counter (ws is poisoned 0xAA before each launch)
// ---------------------------------------------------------------------------
__global__ void init_kernel(unsigned* __restrict__ cnt) {
    if (threadIdx.x == 0)
        __hip_atomic_store(cnt, 0u, __ATOMIC_RELAXED, __HIP_MEMORY_SCOPE_AGENT);
}

// ---------------------------------------------------------------------------
// One map: h-pass straight from global (registers) -> TR LDS rows (contiguous
// b128), v-pass 4 rows/wave into acc. R = tap radius (compile-time).
// ---------------------------------------------------------------------------
template<int R>
static __device__ __forceinline__ void process_map(const float* __restrict__ xc,
                                                   float* __restrict__ tmp,
                                                   int ti0, int tid, int wv, int c,
                                                   float inv2s2,
                                                   float4 acc[4], float& lmax) {
    float w[R + 1];
#pragma unroll
    for (int d = 0; d <= R; ++d) w[d] = expf(-(float)(d * d) * inv2s2);

    constexpr int TR = OROWS + 2 * R;

    // ---- h-stage: TR rows x 32 groups (8 outputs each) ----
#pragma unroll
    for (int t = 0; t < (TR * 32 + 255) / 256; ++t) {
        int idx = tid + t * 256;
        if (idx < TR * 32) {
            int r = idx >> 5;                // tmp row
            int g = idx & 31;                // cols 8g..8g+7
            int gi = ti0 + r - R;            // image row
            float4 q0 = make_float4(0.f,0.f,0.f,0.f), q1 = q0, q2 = q0, q3 = q0;
            if (gi >= 0 && gi < HH) {
                const float4* row = (const float4*)(xc + ((size_t)gi << 8));
                int i0 = (g > 0) ? (2 * g - 1) : 0;
                int i3 = (g < 31) ? (2 * g + 2) : 63;
                q0 = row[i0];
                q1 = row[2 * g];
                q2 = row[2 * g + 1];
                q3 = row[i3];
                if (g == 0)  q0 = make_float4(0.f,0.f,0.f,0.f);
                if (g == 31) q3 = make_float4(0.f,0.f,0.f,0.f);
            }
            float a[16] = {bin(q0.x), bin(q0.y), bin(q0.z), bin(q0.w),
                           bin(q1.x), bin(q1.y), bin(q1.z), bin(q1.w),
                           bin(q2.x), bin(q2.y), bin(q2.z), bin(q2.w),
                           bin(q3.x), bin(q3.y), bin(q3.z), bin(q3.w)};
            float o[8];
#pragma unroll
            for (int j = 0; j < 8; ++j) {
                float s = w[0] * a[j + 4];
#pragma unroll
                for (int d = 1; d <= R; ++d)
                    s += w[d] * (a[j + 4 - d] + a[j + 4 + d]);
                o[j] = s;
            }
            float* trow = &tmp[r * TSTR + 8 * g];
            *(float4*)trow       = make_float4(o[0], o[1], o[2], o[3]);
            *(float4*)(trow + 4) = make_float4(o[4], o[5], o[6], o[7]);
        }
    }
    __syncthreads();

    // ---- v-stage: wave wv -> local out rows 4wv+rr, lane c -> cols 4c..4c+3 ----
#pragma unroll
    for (int rr = 0; rr < 4; ++rr) acc[rr] = make_float4(0.f,0.f,0.f,0.f);
#pragma unroll
    for (int k = 0; k < 4 + 2 * R; ++k) {    // contiguous b128, all lanes same row
        float4 v = *(const float4*)&tmp[(4 * wv + k) * TSTR + 4 * c];
#pragma unroll
        for (int rr = 0; rr < 4; ++rr) {
            int d = k - rr - R;              // compile-time; dead taps pruned
            if (d >= -R && d <= R) {
                float wk = w[d < 0 ? -d : d];
                acc[rr].x += wk * v.x; acc[rr].y += wk * v.y;
                acc[rr].z += wk * v.z; acc[rr].w += wk * v.w;
            }
        }
    }
    lmax = 0.0f;
#pragma unroll
    for (int rr = 0; rr < 4; ++rr)
        lmax = fmaxf(lmax, fmaxf(fmaxf(acc[rr].x, acc[rr].y),
                                 fmaxf(acc[rr].z, acc[rr].w)));
    __syncthreads();                          // tmp reused by next map
}

// ---------------------------------------------------------------------------
// Fused splat + normalize, single kernel with a manual device-scope grid
// barrier (all 1024 blocks co-resident: launch_bounds(256,4) -> 4 blocks/CU,
// LDS 22.9 KB -> not limiting). Only 24 floats/batch cross the barrier.
// map 0: splat(x[:,2],s=1)->ch1 ; 1: x[:,1]->ch2 ; 2: x[:,3],s=.5->ch3 (R=2)
// ---------------------------------------------------------------------------
__global__ __launch_bounds__(256, 4) void fused_kernel(const float* __restrict__ x,
                                                       float* __restrict__ out,
                                                       float* __restrict__ maxws,
                                                       unsigned* __restrict__ cnt) {
    __shared__ float tmp[(OROWS + 6) * TSTR];   // 22*260*4 = 22880 B
    __shared__ float wred[12];                  // 4 waves x 3 maps

    const int blk = blockIdx.x;
    const int b = blk >> 4;
    const int strip = blk & 15;
    const int ti0 = strip * OROWS;
    const int tid = threadIdx.x;
    const int c = tid & 63;
    const int wv = tid >> 6;

    const float* xb = x + ((size_t)b * 4 << 16);
    float4 acc[3][4];
    float lmax[3];

    process_map<3>(xb + (2 << 16), tmp, ti0, tid, wv, c, 0.5f, acc[0], lmax[0]);
    process_map<3>(xb + (1 << 16), tmp, ti0, tid, wv, c, 0.5f, acc[1], lmax[1]);
    process_map<2>(xb + (3 << 16), tmp, ti0, tid, wv, c, 2.0f, acc[2], lmax[2]);

    // ---- block max -> maxws (agent-scope stores; only data crossing barrier) ----
#pragma unroll
    for (int m = 0; m < 3; ++m) {
#pragma unroll
        for (int off = 32; off > 0; off >>= 1)
            lmax[m] = fmaxf(lmax[m], __shfl_down(lmax[m], off, 64));
    }
    if (c == 0) {
        wred[wv * 3 + 0] = lmax[0];
        wred[wv * 3 + 1] = lmax[1];
        wred[wv * 3 + 2] = lmax[2];
    }
    __syncthreads();
    if (tid < 3) {
        float bm = fmaxf(fmaxf(wred[tid], wred[3 + tid]),
                         fmaxf(wred[6 + tid], wred[9 + tid]));
        __hip_atomic_store(&maxws[b * 48 + tid * 16 + strip], bm,
                           __ATOMIC_RELAXED, __HIP_MEMORY_SCOPE_AGENT);
    }

    // ---- manual grid barrier: arrive (release) + spin (acquire) ----
    __syncthreads();
    if (tid == 0) {
        __threadfence();   // flush this block's writes to the coherence point
        __hip_atomic_fetch_add(cnt, 1u, __ATOMIC_RELEASE, __HIP_MEMORY_SCOPE_AGENT);
        long guard = 0;
        while (__hip_atomic_load(cnt, __ATOMIC_ACQUIRE, __HIP_MEMORY_SCOPE_AGENT) < NBLK
               && ++guard < (1L << 24)) { /* spin; guard ~ hang-safety */ }
    }
    __syncthreads();

    // ---- reduce 48 strip-maxes for this batch (agent-scope loads: coherent) ----
    if (tid < 48)
        tmp[tid] = __hip_atomic_load(&maxws[b * 48 + tid],
                                     __ATOMIC_RELAXED, __HIP_MEMORY_SCOPE_AGENT);
    __syncthreads();
    float rmx[3];
#pragma unroll
    for (int m = 0; m < 3; ++m) {
        float mx = 0.0f;
#pragma unroll
        for (int s = 0; s < 16; ++s) mx = fmaxf(mx, tmp[m * 16 + s]);  // broadcast
        if (mx == 0.0f) mx = 1.0f;
        rmx[m] = 1.0f / mx;
    }

    // ---- normalize from registers, write ch1..4 ----
    float* ob = out + ((size_t)b * 5 << 16);
#pragma unroll
    for (int rr = 0; rr < 4; ++rr) {
        int row = ti0 + 4 * wv + rr;
        size_t off = ((size_t)row << 8) + 4 * c;
        float4 t = acc[0][rr], cc = acc[1][rr], h = acc[2][rr];
        t.x *= rmx[0]; t.y *= rmx[0]; t.z *= rmx[0]; t.w *= rmx[0];
        cc.x *= rmx[1]; cc.y *= rmx[1]; cc.z *= rmx[1]; cc.w *= rmx[1];
        h.x *= rmx[2]; h.y *= rmx[2]; h.z *= rmx[2]; h.w *= rmx[2];
        float4 mul = make_float4(t.x * cc.x, t.y * cc.y, t.z * cc.z, t.w * cc.w);
        *(float4*)&ob[(1 << 16) + off] = t;
        *(float4*)&ob[(2 << 16) + off] = cc;
        *(float4*)&ob[(3 << 16) + off] = h;
        *(float4*)&ob[(4 << 16) + off] = mul;
    }

    // ---- ch0 copy for this strip: 1024 float4 ----
    const float4* x0 = (const float4*)xb;
    float4* o0 = (float4*)ob;
#pragma unroll
    for (int i = 0; i < 4; ++i) {
        int q = strip * 1024 + i * 256 + tid;
        o0[q] = x0[q];
    }
}

extern "C" void kernel_launch(void* const* d_in, const int* in_sizes, int n_in,
                              void* d_out, int out_size, void* d_ws, size_t ws_size,
                              hipStream_t stream) {
    const float* x = (const float*)d_in[0];
    float* out = (float*)d_out;
    float* maxws = (float*)d_ws;                          // 64*48 floats = 12288 B
    unsigned* cnt = (unsigned*)((char*)d_ws + 16384);     // barrier counter

    hipLaunchKernelGGL(init_kernel, dim3(1), dim3(64), 0, stream, cnt);
    hipLaunchKernelGGL(fused_kernel, dim3(NBLK), dim3(256), 0, stream,
                       x, out, maxws, cnt);
}